// Round 1
// 264.356 us; speedup vs baseline: 1.0462x; 1.0462x over previous
//
#include <hip/hip_runtime.h>
#include <hip/hip_bf16.h>
#include <cstdint>
#include <cstddef>

typedef short bf16x8 __attribute__((ext_vector_type(8)));
typedef short bf16x4v __attribute__((ext_vector_type(4)));
typedef float f32x4 __attribute__((ext_vector_type(4)));
typedef unsigned int uint32x2 __attribute__((ext_vector_type(2)));
typedef __hip_bfloat16 bf16;

constexpr int Bb = 2, Ss = 2048, Dd = 1024, Hh = 16, DKk = 64;

__device__ __forceinline__ void async_lds16(void* lds, const void* g) {
  __builtin_amdgcn_global_load_lds(
      (const __attribute__((address_space(1))) void*)g,
      (__attribute__((address_space(3))) void*)lds, 16, 0, 0);
}

__device__ __forceinline__ float bf2f(bf16 x) { return __bfloat162float(x); }
__device__ __forceinline__ short f2bf(float x) {         // RNE (lib)
  bf16 h = __float2bfloat16(x);
  return *(short*)&h;
}
// fast round-to-nearest bf16 (values known finite)
__device__ __forceinline__ short f2bf_fast(float x) {
  return (short)((__float_as_uint(x) + 0x8000u) >> 16);
}
__device__ __forceinline__ float bfs2f(short s) {
  return __uint_as_float(((uint32_t)(uint16_t)s) << 16);
}
// packed f32x2 -> bf16x2 (RNE), single VALU op
__device__ __forceinline__ uint32_t cvtpk_bf16(float lo, float hi) {
  uint32_t r;
  asm("v_cvt_pk_bf16_f32 %0, %1, %2" : "=v"(r) : "v"(lo), "v"(hi));
  return r;
}
// permlane swaps: vdst-UPPER block exchanges with vsrc-LOWER block.
// pl32: D[32:63] <-> S[0:31]  => ret.x = [D_lo|S_lo], ret.y = [D_hi|S_hi]
// pl16: D[16:31]<->S[0:15], D[48:63]<->S[32:47]
//       => ret.x = [D0,S0,D2,S2] (16-lane groups), ret.y = [D1,S1,D3,S3]
__device__ __forceinline__ uint32x2 pl32swap(uint32_t d, uint32_t s) {
  return __builtin_amdgcn_permlane32_swap(d, s, false, false);
}
__device__ __forceinline__ uint32x2 pl16swap(uint32_t d, uint32_t s) {
  return __builtin_amdgcn_permlane16_swap(d, s, false, false);
}

// ---------------------------------------------------------------------------
// f32 -> bf16 conversion for 11 tensors + mask bit-pack (job 11).
// grid (1024, 12).
// ---------------------------------------------------------------------------
struct CvtArgs {
  const float* src[12];
  short* dst[12];
  int n[12];
  int count;
};

__global__ __launch_bounds__(256)
void cvt_all(CvtArgs a, const int* __restrict__ mask, uint32_t* __restrict__ bits)
{
  const int t = blockIdx.y;
  if (t == 11) {
    // pack B*S*S = 8388608 mask ints into bits; 32 uniform iterations
    const int stride = 1024 * 256;
    int i = blockIdx.x * 256 + threadIdx.x;
#pragma unroll 4
    for (int it = 0; it < 32; ++it, i += stride) {
      const unsigned long long bal = __ballot(mask[i] != 0);
      if ((threadIdx.x & 63) == 0)
        *(unsigned long long*)(bits + (i >> 5)) = bal;
    }
    return;
  }
  if (t >= a.count) return;
  const float* s = a.src[t];
  short* d = a.dst[t];
  const int n = a.n[t];
  const int stride = gridDim.x * blockDim.x * 4;
  for (int i = (blockIdx.x * blockDim.x + threadIdx.x) * 4; i < n; i += stride) {
    const float4 v = *(const float4*)(s + i);
    bf16x4v o;
    o[0] = f2bf(v.x); o[1] = f2bf(v.y); o[2] = f2bf(v.z); o[3] = f2bf(v.w);
    *(bf16x4v*)(d + i) = o;
  }
}

// ---------------------------------------------------------------------------
// QKV GEMM: Out[m][n] = (sum_k A[m][k]*W[n][k] + bias[n]) * scale, bf16 in,
// bf16 out. mat==2 + vtrans: per-head transposed V via LDS:
// VpT[b][h*64+dk][s].  M=4096, N=1024, K=1024. grid (32, 24).
// launch_bounds(256,3): 3 waves/EU (2nd arg is waves/EU, not blocks/CU!)
// ---------------------------------------------------------------------------
__global__ __launch_bounds__(256, 3)
void gemm_bt(const bf16* __restrict__ A0, const bf16* __restrict__ A1, const bf16* __restrict__ A2,
             const bf16* __restrict__ W0, const bf16* __restrict__ W1, const bf16* __restrict__ W2,
             const bf16* __restrict__ b0, const bf16* __restrict__ b1, const bf16* __restrict__ b2,
             void* __restrict__ O0, void* __restrict__ O1, void* __restrict__ O2,
             float scale0, int vtrans)
{
  extern __shared__ char smem[];
  const int mt  = blockIdx.x;
  const int by  = blockIdx.y;
  const int mat = by >> 3;
  const int nt  = by & 7;
  const bf16* A    = (mat == 0) ? A0 : (mat == 1) ? A1 : A2;
  const bf16* W    = (mat == 0) ? W0 : (mat == 1) ? W1 : W2;
  const bf16* bias = (mat == 0) ? b0 : (mat == 1) ? b1 : b2;
  void*       Out  = (mat == 0) ? O0 : (mat == 1) ? O1 : O2;
  const float scale = (mat == 0) ? scale0 : 1.0f;

  const int tid  = threadIdx.x;
  const int w    = tid >> 6;
  const int lane = tid & 63;
  const int quad = lane >> 4;
  const int l16  = lane & 15;
  const int wm   = (w & 1) * 64;
  const int wn   = (w >> 1) * 64;

  const int srow = lane >> 3;
  const int sseg = (lane & 7) ^ srow;

  const char* Abytes = (const char*)A;
  const char* Wbytes = (const char*)W;

  f32x4 acc[4][4];
#pragma unroll
  for (int i = 0; i < 4; ++i)
#pragma unroll
    for (int j = 0; j < 4; ++j) acc[i][j] = f32x4{0.f, 0.f, 0.f, 0.f};

  for (int kt = 0; kt < 16; ++kt) {
    __syncthreads();
#pragma unroll
    for (int c = 0; c < 4; ++c) {
      const int r0 = w * 32 + c * 8;
      async_lds16(smem + r0 * 128,
                  Abytes + (size_t)(mt * 128 + r0 + srow) * 2048 + kt * 128 + sseg * 16);
      async_lds16(smem + 16384 + r0 * 128,
                  Wbytes + (size_t)(nt * 128 + r0 + srow) * 2048 + kt * 128 + sseg * 16);
    }
    __syncthreads();
#pragma unroll
    for (int s = 0; s < 2; ++s) {
      bf16x8 af[4], bfg[4];
#pragma unroll
      for (int mb = 0; mb < 4; ++mb) {
        const int row = wm + mb * 16 + l16;
        af[mb] = *(const bf16x8*)(smem + row * 128 + (((4 * s + quad) ^ (row & 7)) * 16));
      }
#pragma unroll
      for (int nb = 0; nb < 4; ++nb) {
        const int row = wn + nb * 16 + l16;
        bfg[nb] = *(const bf16x8*)(smem + 16384 + row * 128 + (((4 * s + quad) ^ (row & 7)) * 16));
      }
#pragma unroll
      for (int mb = 0; mb < 4; ++mb)
#pragma unroll
        for (int nb = 0; nb < 4; ++nb)
          acc[mb][nb] = __builtin_amdgcn_mfma_f32_16x16x32_bf16(af[mb], bfg[nb], acc[mb][nb], 0, 0, 0);
    }
  }

  if (vtrans && mat == 2) {
    // stage tile transposed in LDS: T[dk][s] 128 x 256B, 16B-seg XOR by dk&15
    __syncthreads();
#pragma unroll
    for (int nb = 0; nb < 4; ++nb) {
      const int dk = wn + nb * 16 + l16;
      const float bv = bf2f(bias[nt * 128 + dk]);
#pragma unroll
      for (int mb = 0; mb < 4; ++mb) {
        const int s0 = wm + mb * 16 + quad * 4;
        bf16x4v pk;
#pragma unroll
        for (int r = 0; r < 4; ++r) pk[r] = f2bf_fast(acc[mb][nb][r] + bv);
        *(bf16x4v*)(smem + dk * 256 + (((s0 >> 3) ^ (dk & 15)) * 16) + (s0 & 7) * 2) = pk;
      }
    }
    __syncthreads();
    const int bidx  = (mt * 128) >> 11;
    const int sbase = (mt * 128) & 2047;
#pragma unroll
    for (int i = 0; i < 8; ++i) {
      const int dk  = i * 16 + (tid >> 4);
      const int seg = tid & 15;
      bf16x8 vrow = *(const bf16x8*)(smem + dk * 256 + ((seg ^ (dk & 15)) * 16));
      *(bf16x8*)((bf16*)Out + (size_t)bidx * 2097152 + (size_t)(nt * 128 + dk) * 2048
                 + sbase + seg * 8) = vrow;
    }
  } else {
#pragma unroll
    for (int nb = 0; nb < 4; ++nb) {
      const int col = nt * 128 + wn + nb * 16 + l16;
      const float bv = bf2f(bias[col]);
#pragma unroll
      for (int mb = 0; mb < 4; ++mb) {
#pragma unroll
        for (int r = 0; r < 4; ++r) {
          const int row = mt * 128 + wm + mb * 16 + quad * 4 + r;
          short s = f2bf_fast((acc[mb][nb][r] + bv) * scale);
          ((short*)Out)[(size_t)row * 1024 + col] = s;
        }
      }
    }
  }
}

// ---------------------------------------------------------------------------
// Output projection GEMM, 64x64 tiles for occupancy: out[m][n] =
// sum_k Xa[m][k]*Wo[n][k] + bo[n], f32 out. grid (64, 16) = 1024 blocks
// = 4 blocks/CU.
// ---------------------------------------------------------------------------
__global__ __launch_bounds__(256, 4)
void gemm_out(const bf16* __restrict__ A, const bf16* __restrict__ W,
              const bf16* __restrict__ bias, float* __restrict__ Out)
{
  __shared__ char smem[16384];
  const int mt = blockIdx.x;
  const int nt = blockIdx.y;
  const int tid = threadIdx.x, w = tid >> 6, lane = tid & 63;
  const int quad = lane >> 4, l16 = lane & 15;
  const int wm = (w & 1) * 32, wn = (w >> 1) * 32;
  const int srow = lane >> 3;
  const int sseg = (lane & 7) ^ (srow & 7);

  const char* Abytes = (const char*)A;
  const char* Wbytes = (const char*)W;

  f32x4 acc[2][2];
#pragma unroll
  for (int i = 0; i < 2; ++i)
#pragma unroll
    for (int j = 0; j < 2; ++j) acc[i][j] = f32x4{0.f, 0.f, 0.f, 0.f};

  for (int kt = 0; kt < 16; ++kt) {
    __syncthreads();
#pragma unroll
    for (int c = 0; c < 2; ++c) {
      const int r0 = c * 32 + w * 8;
      async_lds16(smem + c * 4096 + w * 1024,
                  Abytes + (size_t)(mt * 64 + r0 + srow) * 2048 + kt * 128 + sseg * 16);
      async_lds16(smem + 8192 + c * 4096 + w * 1024,
                  Wbytes + (size_t)(nt * 64 + r0 + srow) * 2048 + kt * 128 + sseg * 16);
    }
    __syncthreads();
#pragma unroll
    for (int s = 0; s < 2; ++s) {
      bf16x8 af[2], bfg[2];
#pragma unroll
      for (int mb = 0; mb < 2; ++mb) {
        const int row = wm + mb * 16 + l16;
        af[mb] = *(const bf16x8*)(smem + row * 128 + (((4 * s + quad) ^ (row & 7)) * 16));
      }
#pragma unroll
      for (int nb = 0; nb < 2; ++nb) {
        const int row = wn + nb * 16 + l16;
        bfg[nb] = *(const bf16x8*)(smem + 8192 + row * 128 + (((4 * s + quad) ^ (row & 7)) * 16));
      }
#pragma unroll
      for (int mb = 0; mb < 2; ++mb)
#pragma unroll
        for (int nb = 0; nb < 2; ++nb)
          acc[mb][nb] = __builtin_amdgcn_mfma_f32_16x16x32_bf16(af[mb], bfg[nb], acc[mb][nb], 0, 0, 0);
    }
  }

#pragma unroll
  for (int nb = 0; nb < 2; ++nb) {
    const int col = nt * 64 + wn + nb * 16 + l16;
    const float bv = bf2f(bias[col]);
#pragma unroll
    for (int mb = 0; mb < 2; ++mb) {
#pragma unroll
      for (int r = 0; r < 4; ++r) {
        const int row = mt * 64 + wm + mb * 16 + quad * 4 + r;
        Out[(size_t)row * 1024 + col] = acc[mb][nb][r] + bv;
      }
    }
  }
}

// ---------------------------------------------------------------------------
// Split-K flash attention, fixed-base softmax (base 2: Q pre-scaled by
// log2e/8). 128-q tiles, 32 q per wave. Transposed QK MFMA (C: col=q,
// row=key). P kept ENTIRELY in registers: per 32-key slice, 4 cvt_pk +
// 2 permlane32_swap + 2 permlane16_swap redistribute the quad-local
// sc values (keys quad*4+r) into the PV A-frag layout (keys quad*8+j).
// No P LDS, no 3rd barrier. LDS 32KB: K 16KB @0, Vt 16KB @16384
// -> 4 blocks/CU (VGPR-capped via launch_bounds(256,4)).
// ---------------------------------------------------------------------------
__global__ __launch_bounds__(256, 4)
void attn(const bf16* __restrict__ Qp, const bf16* __restrict__ Kp,
          const bf16* __restrict__ VpT, const uint32_t* __restrict__ mbits,
          bf16* __restrict__ Opart, float* __restrict__ Lpart)
{
  __shared__ char smem[32768];
  char* Kb = smem;           // K tile 128 rows x 128B, XOR-swizzled (row&7)
  char* Vt = smem + 16384;   // V^T 64 rows x 256B, XOR-swizzled (row&15)

  const int tile  = blockIdx.x;           // 512 = b*256 + h*16 + qt
  const int split = blockIdx.y;           // 3
  const int qt = tile & 15, h = (tile >> 4) & 15, b = tile >> 8;
  const int tid = threadIdx.x, w = tid >> 6, lane = tid & 63;
  const int quad = lane >> 4, l16 = lane & 15;
  const int qb = qt * 128;
  const size_t headoff = (size_t)b * (Ss * Dd) + h * DKk;

  const int kc0 = (split == 0) ? 0 : (split == 1) ? 6 : 11;
  const int kc1 = (split == 0) ? 6 : (split == 1) ? 11 : 16;

  // Q B-frags, two sets of 16 q: lane holds Q[q][k = s2*32 + quad*8 + j]
  bf16x8 qf[2][2];
#pragma unroll
  for (int set = 0; set < 2; ++set)
#pragma unroll
    for (int s2 = 0; s2 < 2; ++s2) {
      const int row = qb + w * 32 + set * 16 + l16;
      qf[set][s2] = *(const bf16x8*)(Qp + headoff + (size_t)row * Dd + s2 * 32 + quad * 8);
    }

  f32x4 o[2][4];
  float Lacc[2] = {0.f, 0.f};
#pragma unroll
  for (int set = 0; set < 2; ++set)
#pragma unroll
    for (int nbk = 0; nbk < 4; ++nbk) o[set][nbk] = f32x4{0.f, 0.f, 0.f, 0.f};

  const uint32_t* mrow0 = mbits + (size_t)(b * Ss + qb + w * 32 + l16) * 64;
  const uint32_t* mrow1 = mrow0 + 16 * 64;

  for (int kc = kc0; kc < kc1; ++kc) {
    const int kb = kc * 128;
    __syncthreads();   // prior chunk's K/Vt reads done before restaging
#pragma unroll
    for (int c = 0; c < 4; ++c) {
      {
        const int row = c * 32 + w * 8 + (lane >> 3);
        const int seg = (lane & 7) ^ (row & 7);
        async_lds16(Kb + c * 4096 + w * 1024,
                    Kp + headoff + (size_t)(kb + row) * Dd + seg * 8);
      }
      {
        const int row = c * 16 + w * 4 + (lane >> 4);
        const int seg = (lane & 15) ^ (row & 15);
        async_lds16(Vt + c * 4096 + w * 1024,
                    VpT + (size_t)b * 2097152 + (size_t)(h * 64 + row) * 2048 + kb + seg * 8);
      }
    }
    __syncthreads();   // staging complete (syncthreads drains vmcnt)

    const uint4 mwv0 = *(const uint4*)(mrow0 + kc * 4);
    const uint4 mwv1 = *(const uint4*)(mrow1 + kc * 4);
    const uint32_t mw0[4] = {mwv0.x, mwv0.y, mwv0.z, mwv0.w};
    const uint32_t mw1[4] = {mwv1.x, mwv1.y, mwv1.z, mwv1.w};

    // per 32-key slice: QK -> masked exp2 -> in-reg P frag -> PV
#pragma unroll
    for (int sl = 0; sl < 4; ++sl) {
      f32x4 sc[2][2];
#pragma unroll
      for (int set = 0; set < 2; ++set)
#pragma unroll
        for (int nbh = 0; nbh < 2; ++nbh) sc[set][nbh] = f32x4{0.f, 0.f, 0.f, 0.f};
#pragma unroll
      for (int s2 = 0; s2 < 2; ++s2)
#pragma unroll
        for (int nbh = 0; nbh < 2; ++nbh) {
          const int row = (sl * 2 + nbh) * 16 + l16;
          bf16x8 kf = *(const bf16x8*)(Kb + row * 128 + (((s2 * 4 + quad) ^ (row & 7)) * 16));
          sc[0][nbh] = __builtin_amdgcn_mfma_f32_16x16x32_bf16(kf, qf[0][s2], sc[0][nbh], 0, 0, 0);
          sc[1][nbh] = __builtin_amdgcn_mfma_f32_16x16x32_bf16(kf, qf[1][s2], sc[1][nbh], 0, 0, 0);
        }

      bf16x8 pf[2];
#pragma unroll
      for (int set = 0; set < 2; ++set) {
        const uint32_t mword = (set == 0) ? mw0[sl] : mw1[sl];
        uint32_t pk[2][2];   // [nbh][word]: quad q holds keys nb*16+q*4+{0..3}
        float Ls = 0.f;
#pragma unroll
        for (int nbh = 0; nbh < 2; ++nbh) {
          const uint32_t nib = (mword >> (nbh * 16 + quad * 4)) & 0xFu;
          const float e0 = __builtin_amdgcn_exp2f(sc[set][nbh][0]);
          const float e1 = __builtin_amdgcn_exp2f(sc[set][nbh][1]);
          const float e2 = __builtin_amdgcn_exp2f(sc[set][nbh][2]);
          const float e3 = __builtin_amdgcn_exp2f(sc[set][nbh][3]);
          const float p0 = (nib & 1u) ? e0 : 0.f;
          const float p1 = (nib & 2u) ? e1 : 0.f;
          const float p2 = (nib & 4u) ? e2 : 0.f;
          const float p3 = (nib & 8u) ? e3 : 0.f;
          Ls += (p0 + p1) + (p2 + p3);
          pk[nbh][0] = cvtpk_bf16(p0, p1);
          pk[nbh][1] = cvtpk_bf16(p2, p3);
        }
        Lacc[set] += Ls;
        // quad redistribution: source quad q has keys q*4+{0..3} per nb;
        // target quad q needs keys q*8+{0..7} of the 32-key slice.
        // step1 (pl32, D=lo-nb S=hi-nb): .x=[A,B|E,F], .y=[C,D|G,H]
        // step2 (pl16, D=.x S=.y):      .x=[A,C,E,G], .y=[B,D,F,H]
        const uint32x2 r0 = pl32swap(pk[0][0], pk[1][0]);
        const uint32x2 r1 = pl32swap(pk[0][1], pk[1][1]);
        const uint32x2 t0 = pl16swap(r0.x, r0.y);
        const uint32x2 t1 = pl16swap(r1.x, r1.y);
        union { uint32_t u[4]; bf16x8 v; } U;
        U.u[0] = t0.x; U.u[1] = t1.x; U.u[2] = t0.y; U.u[3] = t1.y;
        pf[set] = U.v;
      }

      // PV for this slice; vf shared across both q-sets
#pragma unroll
      for (int nbk = 0; nbk < 4; ++nbk) {
        const int row = nbk * 16 + l16;
        bf16x8 vf = *(const bf16x8*)(Vt + row * 256 + (((sl * 4 + quad) ^ (row & 15)) * 16));
        o[0][nbk] = __builtin_amdgcn_mfma_f32_16x16x32_bf16(pf[0], vf, o[0][nbk], 0, 0, 0);
        o[1][nbk] = __builtin_amdgcn_mfma_f32_16x16x32_bf16(pf[1], vf, o[1][nbk], 0, 0, 0);
      }
    }
  }

  // epilogue: reduce L over quads, write partials (rows = tile*128 + qlocal)
#pragma unroll
  for (int set = 0; set < 2; ++set) {
    float Lq = Lacc[set];
    Lq += __shfl_xor(Lq, 16);
    Lq += __shfl_xor(Lq, 32);
    const int rbase = tile * 128 + w * 32 + set * 16;
#pragma unroll
    for (int r = 0; r < 4; ++r) {
      const int rglob = rbase + quad * 4 + r;
#pragma unroll
      for (int nbk = 0; nbk < 4; ++nbk) {
        short s = f2bf_fast(o[set][nbk][r]);
        ((short*)Opart)[((size_t)split * 65536 + rglob) * 64 + nbk * 16 + l16] = s;
      }
    }
    if (quad == 0)
      Lpart[(size_t)split * 65536 + rbase + l16] = Lq;
  }
}

// ---------------------------------------------------------------------------
// Combine 3 split partials (plain sums) -> Xa[b*S+q][h*64+dk] bf16.
// ---------------------------------------------------------------------------
__global__ __launch_bounds__(256)
void combine(const bf16* __restrict__ Opart, const float* __restrict__ Lpart,
             bf16* __restrict__ Xa)
{
  const int t = threadIdx.x;
  const int row = blockIdx.x * 32 + (t >> 3);     // 0..65535
  const int dkc = (t & 7) * 8;
  const float L = Lpart[row] + Lpart[65536 + row] + Lpart[131072 + row];
  const float inv = 1.0f / L;
  const bf16x8 O0 = *(const bf16x8*)(Opart + (size_t)row * 64 + dkc);
  const bf16x8 O1 = *(const bf16x8*)(Opart + ((size_t)65536 + row) * 64 + dkc);
  const bf16x8 O2 = *(const bf16x8*)(Opart + ((size_t)131072 + row) * 64 + dkc);
  bf16x8 res;
#pragma unroll
  for (int j = 0; j < 8; ++j)
    res[j] = f2bf_fast((bfs2f(O0[j]) + bfs2f(O1[j]) + bfs2f(O2[j])) * inv);
  const int tile = row >> 7, qlocal = row & 127;
  const int b = tile >> 8, h = (tile >> 4) & 15, q = (tile & 15) * 128 + qlocal;
  *(bf16x8*)(Xa + (size_t)(b * 2048 + q) * 1024 + h * 64 + dkc) = res;
}

// ---------------------------------------------------------------------------
extern "C" void kernel_launch(void* const* d_in, const int* in_sizes, int n_in,
                              void* d_out, int out_size, void* d_ws, size_t ws_size,
                              hipStream_t stream)
{
  const float* q  = (const float*)d_in[0];
  const float* k  = (const float*)d_in[1];
  const float* v  = (const float*)d_in[2];
  const int*   mk = (const int*)d_in[3];
  const float* wq = (const float*)d_in[4];
  const float* bq = (const float*)d_in[5];
  const float* wk = (const float*)d_in[6];
  const float* bk = (const float*)d_in[7];
  const float* wv = (const float*)d_in[8];
  const float* bv = (const float*)d_in[9];
  const float* wo = (const float*)d_in[10];
  const float* bo = (const float*)d_in[11];
  float* out = (float*)d_out;

  char* ws = (char*)d_ws;
  // phase-1 buffers
  bf16* qb_  = (bf16*)(ws + ((size_t)0  << 20));
  bf16* kb_  = (bf16*)(ws + ((size_t)8  << 20));
  bf16* vb_  = (bf16*)(ws + ((size_t)16 << 20));
  bf16* Qp   = (bf16*)(ws + ((size_t)24 << 20));
  bf16* Kp   = (bf16*)(ws + ((size_t)32 << 20));
  bf16* VpT  = (bf16*)(ws + ((size_t)40 << 20));
  bf16* wqb  = (bf16*)(ws + ((size_t)48 << 20));
  bf16* wkb  = (bf16*)(ws + ((size_t)50 << 20));
  bf16* wvb  = (bf16*)(ws + ((size_t)52 << 20));
  bf16* wob  = (bf16*)(ws + ((size_t)54 << 20));
  bf16* bqb  = (bf16*)(ws + ((size_t)56 << 20));
  bf16* bkb  = (bf16*)(ws + ((size_t)56 << 20) + 2048);
  bf16* bvb  = (bf16*)(ws + ((size_t)56 << 20) + 4096);
  bf16* bob  = (bf16*)(ws + ((size_t)56 << 20) + 6144);
  uint32_t* mbits = (uint32_t*)(ws + ((size_t)56 << 20) + 65536);  // 1 MB
  // phase-2 overlays: Opart 24MB over qb_/kb_/vb_ (dead after QKV GEMM);
  // Lpart 0.75MB over wqb/wkb (dead); Xa 8MB over Qp (dead after attn)
  bf16*  Opart = (bf16*)(ws + ((size_t)0 << 20));
  float* Lpart = (float*)(ws + ((size_t)48 << 20));
  bf16*  Xa    = (bf16*)(ws + ((size_t)24 << 20));

  const int NA = Bb * Ss * Dd;  // 4194304
  const int NW = Dd * Dd;       // 1048576

  CvtArgs ca;
  ca.src[0] = q;  ca.dst[0] = (short*)qb_; ca.n[0] = NA;
  ca.src[1] = k;  ca.dst[1] = (short*)kb_; ca.n[1] = NA;
  ca.src[2] = v;  ca.dst[2] = (short*)vb_; ca.n[2] = NA;
  ca.src[3] = wq; ca.dst[3] = (short*)wqb; ca.n[3] = NW;
  ca.src[4] = wk; ca.dst[4] = (short*)wkb; ca.n[4] = NW;
  ca.src[5] = wv; ca.dst[5] = (short*)wvb; ca.n[5] = NW;
  ca.src[6] = wo; ca.dst[6] = (short*)wob; ca.n[6] = NW;
  ca.src[7] = bq; ca.dst[7] = (short*)bqb; ca.n[7] = Dd;
  ca.src[8] = bk; ca.dst[8] = (short*)bkb; ca.n[8] = Dd;
  ca.src[9] = bv; ca.dst[9] = (short*)bvb; ca.n[9] = Dd;
  ca.src[10] = bo; ca.dst[10] = (short*)bob; ca.n[10] = Dd;
  ca.src[11] = bo; ca.dst[11] = (short*)bob; ca.n[11] = 0;
  ca.count = 11;

  dim3 blk(256);
  // conversions + mask pack (job 11) in one launch
  cvt_all<<<dim3(1024, 12), blk, 0, stream>>>(ca, mk, mbits);

  // fused QKV projections; Q scaled by log2e/8 (softmax runs in base 2),
  // V written transposed via LDS
  gemm_bt<<<dim3(32, 24), blk, 32768, stream>>>(qb_, kb_, vb_, wqb, wkb, wvb,
                                                bqb, bkb, bvb,
                                                (void*)Qp, (void*)Kp, (void*)VpT,
                                                0.125f * 1.44269504088896340736f, 1);
  // split-K flash attention (3 splits), fixed-base softmax, P in registers
  attn<<<dim3(512, 3), blk, 0, stream>>>(Qp, Kp, VpT, mbits, Opart, Lpart);
  // merge split partials
  combine<<<dim3(2048), blk, 0, stream>>>(Opart, Lpart, Xa);
  // output projection -> f32 d_out (64x64 tiles, 1024 blocks = 4/CU)
  gemm_out<<<dim3(64, 16), blk, 0, stream>>>(Xa, wob, bob, out);
}

// Round 2
// 254.883 us; speedup vs baseline: 1.0851x; 1.0372x over previous
//
#include <hip/hip_runtime.h>
#include <hip/hip_bf16.h>
#include <cstdint>
#include <cstddef>

typedef short bf16x8 __attribute__((ext_vector_type(8)));
typedef short bf16x4v __attribute__((ext_vector_type(4)));
typedef float f32x4 __attribute__((ext_vector_type(4)));
typedef unsigned int uint32x2 __attribute__((ext_vector_type(2)));
typedef __hip_bfloat16 bf16;

constexpr int Bb = 2, Ss = 2048, Dd = 1024, Hh = 16, DKk = 64;

__device__ __forceinline__ void async_lds16(void* lds, const void* g) {
  __builtin_amdgcn_global_load_lds(
      (const __attribute__((address_space(1))) void*)g,
      (__attribute__((address_space(3))) void*)lds, 16, 0, 0);
}

__device__ __forceinline__ float bf2f(bf16 x) { return __bfloat162float(x); }
__device__ __forceinline__ short f2bf(float x) {         // RNE (lib)
  bf16 h = __float2bfloat16(x);
  return *(short*)&h;
}
// fast round-to-nearest bf16 (values known finite)
__device__ __forceinline__ short f2bf_fast(float x) {
  return (short)((__float_as_uint(x) + 0x8000u) >> 16);
}
__device__ __forceinline__ float bfs2f(short s) {
  return __uint_as_float(((uint32_t)(uint16_t)s) << 16);
}
// packed f32x2 -> bf16x2 (RNE), single VALU op
__device__ __forceinline__ uint32_t cvtpk_bf16(float lo, float hi) {
  uint32_t r;
  asm("v_cvt_pk_bf16_f32 %0, %1, %2" : "=v"(r) : "v"(lo), "v"(hi));
  return r;
}
// permlane swaps: vdst-UPPER block exchanges with vsrc-LOWER block.
__device__ __forceinline__ uint32x2 pl32swap(uint32_t d, uint32_t s) {
  return __builtin_amdgcn_permlane32_swap(d, s, false, false);
}
__device__ __forceinline__ uint32x2 pl16swap(uint32_t d, uint32_t s) {
  return __builtin_amdgcn_permlane16_swap(d, s, false, false);
}

// ---------------------------------------------------------------------------
// f32 -> bf16 conversion for 11 tensors + mask bit-pack (job 11).
// grid (1024, 12).
// ---------------------------------------------------------------------------
struct CvtArgs {
  const float* src[12];
  short* dst[12];
  int n[12];
  int count;
};

__global__ __launch_bounds__(256)
void cvt_all(CvtArgs a, const int* __restrict__ mask, uint32_t* __restrict__ bits)
{
  const int t = blockIdx.y;
  if (t == 11) {
    // pack B*S*S = 8388608 mask ints into bits; 32 uniform iterations
    const int stride = 1024 * 256;
    int i = blockIdx.x * 256 + threadIdx.x;
#pragma unroll 4
    for (int it = 0; it < 32; ++it, i += stride) {
      const unsigned long long bal = __ballot(mask[i] != 0);
      if ((threadIdx.x & 63) == 0)
        *(unsigned long long*)(bits + (i >> 5)) = bal;
    }
    return;
  }
  if (t >= a.count) return;
  const float* s = a.src[t];
  short* d = a.dst[t];
  const int n = a.n[t];
  const int stride = gridDim.x * blockDim.x * 4;
  for (int i = (blockIdx.x * blockDim.x + threadIdx.x) * 4; i < n; i += stride) {
    const float4 v = *(const float4*)(s + i);
    bf16x4v o;
    o[0] = f2bf(v.x); o[1] = f2bf(v.y); o[2] = f2bf(v.z); o[3] = f2bf(v.w);
    *(bf16x4v*)(d + i) = o;
  }
}

// ---------------------------------------------------------------------------
// QKV GEMM: Out[m][n] = (sum_k A[m][k]*W[n][k] + bias[n]) * scale, bf16 in,
// bf16 out. mat==2 + vtrans: per-head transposed V via LDS:
// VpT[b][h*64+dk][s].  M=4096, N=1024, K=1024. grid (32, 24).
// ---------------------------------------------------------------------------
__global__ __launch_bounds__(256, 3)
void gemm_bt(const bf16* __restrict__ A0, const bf16* __restrict__ A1, const bf16* __restrict__ A2,
             const bf16* __restrict__ W0, const bf16* __restrict__ W1, const bf16* __restrict__ W2,
             const bf16* __restrict__ b0, const bf16* __restrict__ b1, const bf16* __restrict__ b2,
             void* __restrict__ O0, void* __restrict__ O1, void* __restrict__ O2,
             float scale0, int vtrans)
{
  extern __shared__ char smem[];
  const int mt  = blockIdx.x;
  const int by  = blockIdx.y;
  const int mat = by >> 3;
  const int nt  = by & 7;
  const bf16* A    = (mat == 0) ? A0 : (mat == 1) ? A1 : A2;
  const bf16* W    = (mat == 0) ? W0 : (mat == 1) ? W1 : W2;
  const bf16* bias = (mat == 0) ? b0 : (mat == 1) ? b1 : b2;
  void*       Out  = (mat == 0) ? O0 : (mat == 1) ? O1 : O2;
  const float scale = (mat == 0) ? scale0 : 1.0f;

  const int tid  = threadIdx.x;
  const int w    = tid >> 6;
  const int lane = tid & 63;
  const int quad = lane >> 4;
  const int l16  = lane & 15;
  const int wm   = (w & 1) * 64;
  const int wn   = (w >> 1) * 64;

  const int srow = lane >> 3;
  const int sseg = (lane & 7) ^ srow;

  const char* Abytes = (const char*)A;
  const char* Wbytes = (const char*)W;

  f32x4 acc[4][4];
#pragma unroll
  for (int i = 0; i < 4; ++i)
#pragma unroll
    for (int j = 0; j < 4; ++j) acc[i][j] = f32x4{0.f, 0.f, 0.f, 0.f};

  for (int kt = 0; kt < 16; ++kt) {
    __syncthreads();
#pragma unroll
    for (int c = 0; c < 4; ++c) {
      const int r0 = w * 32 + c * 8;
      async_lds16(smem + r0 * 128,
                  Abytes + (size_t)(mt * 128 + r0 + srow) * 2048 + kt * 128 + sseg * 16);
      async_lds16(smem + 16384 + r0 * 128,
                  Wbytes + (size_t)(nt * 128 + r0 + srow) * 2048 + kt * 128 + sseg * 16);
    }
    __syncthreads();
#pragma unroll
    for (int s = 0; s < 2; ++s) {
      bf16x8 af[4], bfg[4];
#pragma unroll
      for (int mb = 0; mb < 4; ++mb) {
        const int row = wm + mb * 16 + l16;
        af[mb] = *(const bf16x8*)(smem + row * 128 + (((4 * s + quad) ^ (row & 7)) * 16));
      }
#pragma unroll
      for (int nb = 0; nb < 4; ++nb) {
        const int row = wn + nb * 16 + l16;
        bfg[nb] = *(const bf16x8*)(smem + 16384 + row * 128 + (((4 * s + quad) ^ (row & 7)) * 16));
      }
#pragma unroll
      for (int mb = 0; mb < 4; ++mb)
#pragma unroll
        for (int nb = 0; nb < 4; ++nb)
          acc[mb][nb] = __builtin_amdgcn_mfma_f32_16x16x32_bf16(af[mb], bfg[nb], acc[mb][nb], 0, 0, 0);
    }
  }

  if (vtrans && mat == 2) {
    // stage tile transposed in LDS: T[dk][s] 128 x 256B, 16B-seg XOR by dk&15
    __syncthreads();
#pragma unroll
    for (int nb = 0; nb < 4; ++nb) {
      const int dk = wn + nb * 16 + l16;
      const float bv = bf2f(bias[nt * 128 + dk]);
#pragma unroll
      for (int mb = 0; mb < 4; ++mb) {
        const int s0 = wm + mb * 16 + quad * 4;
        bf16x4v pk;
#pragma unroll
        for (int r = 0; r < 4; ++r) pk[r] = f2bf_fast(acc[mb][nb][r] + bv);
        *(bf16x4v*)(smem + dk * 256 + (((s0 >> 3) ^ (dk & 15)) * 16) + (s0 & 7) * 2) = pk;
      }
    }
    __syncthreads();
    const int bidx  = (mt * 128) >> 11;
    const int sbase = (mt * 128) & 2047;
#pragma unroll
    for (int i = 0; i < 8; ++i) {
      const int dk  = i * 16 + (tid >> 4);
      const int seg = tid & 15;
      bf16x8 vrow = *(const bf16x8*)(smem + dk * 256 + ((seg ^ (dk & 15)) * 16));
      *(bf16x8*)((bf16*)Out + (size_t)bidx * 2097152 + (size_t)(nt * 128 + dk) * 2048
                 + sbase + seg * 8) = vrow;
    }
  } else {
#pragma unroll
    for (int nb = 0; nb < 4; ++nb) {
      const int col = nt * 128 + wn + nb * 16 + l16;
      const float bv = bf2f(bias[col]);
#pragma unroll
      for (int mb = 0; mb < 4; ++mb) {
#pragma unroll
        for (int r = 0; r < 4; ++r) {
          const int row = mt * 128 + wm + mb * 16 + quad * 4 + r;
          short s = f2bf_fast((acc[mb][nb][r] + bv) * scale);
          ((short*)Out)[(size_t)row * 1024 + col] = s;
        }
      }
    }
  }
}

// ---------------------------------------------------------------------------
// Output projection GEMM, 64x64 tiles for occupancy. grid (64, 16).
// ---------------------------------------------------------------------------
__global__ __launch_bounds__(256, 4)
void gemm_out(const bf16* __restrict__ A, const bf16* __restrict__ W,
              const bf16* __restrict__ bias, float* __restrict__ Out)
{
  __shared__ char smem[16384];
  const int mt = blockIdx.x;
  const int nt = blockIdx.y;
  const int tid = threadIdx.x, w = tid >> 6, lane = tid & 63;
  const int quad = lane >> 4, l16 = lane & 15;
  const int wm = (w & 1) * 32, wn = (w >> 1) * 32;
  const int srow = lane >> 3;
  const int sseg = (lane & 7) ^ (srow & 7);

  const char* Abytes = (const char*)A;
  const char* Wbytes = (const char*)W;

  f32x4 acc[2][2];
#pragma unroll
  for (int i = 0; i < 2; ++i)
#pragma unroll
    for (int j = 0; j < 2; ++j) acc[i][j] = f32x4{0.f, 0.f, 0.f, 0.f};

  for (int kt = 0; kt < 16; ++kt) {
    __syncthreads();
#pragma unroll
    for (int c = 0; c < 2; ++c) {
      const int r0 = c * 32 + w * 8;
      async_lds16(smem + c * 4096 + w * 1024,
                  Abytes + (size_t)(mt * 64 + r0 + srow) * 2048 + kt * 128 + sseg * 16);
      async_lds16(smem + 8192 + c * 4096 + w * 1024,
                  Wbytes + (size_t)(nt * 64 + r0 + srow) * 2048 + kt * 128 + sseg * 16);
    }
    __syncthreads();
#pragma unroll
    for (int s = 0; s < 2; ++s) {
      bf16x8 af[2], bfg[2];
#pragma unroll
      for (int mb = 0; mb < 2; ++mb) {
        const int row = wm + mb * 16 + l16;
        af[mb] = *(const bf16x8*)(smem + row * 128 + (((4 * s + quad) ^ (row & 7)) * 16));
      }
#pragma unroll
      for (int nb = 0; nb < 2; ++nb) {
        const int row = wn + nb * 16 + l16;
        bfg[nb] = *(const bf16x8*)(smem + 8192 + row * 128 + (((4 * s + quad) ^ (row & 7)) * 16));
      }
#pragma unroll
      for (int mb = 0; mb < 2; ++mb)
#pragma unroll
        for (int nb = 0; nb < 2; ++nb)
          acc[mb][nb] = __builtin_amdgcn_mfma_f32_16x16x32_bf16(af[mb], bfg[nb], acc[mb][nb], 0, 0, 0);
    }
  }

#pragma unroll
  for (int nb = 0; nb < 2; ++nb) {
    const int col = nt * 64 + wn + nb * 16 + l16;
    const float bv = bf2f(bias[col]);
#pragma unroll
    for (int mb = 0; mb < 2; ++mb) {
#pragma unroll
      for (int r = 0; r < 4; ++r) {
        const int row = mt * 64 + wm + mb * 16 + quad * 4 + r;
        Out[(size_t)row * 1024 + col] = acc[mb][nb][r] + bv;
      }
    }
  }
}

// ---------------------------------------------------------------------------
// Split-K flash attention, fixed-base softmax (base 2: Q pre-scaled by
// log2e/8). 2 splits x 8 chunks. 128-q tiles, 32 q per wave.
// K/V double-buffered in LDS (2 x 32KB); per chunk: issue next-chunk
// mask loads + 8 global_load_lds, then counted s_waitcnt vmcnt(8) (the
// prefetch stays in flight across the barrier -- T3/T4), raw s_barrier,
// compute, trailing s_barrier. P entirely in registers (cvt_pk +
// permlane). L computed by an extra MFMA with an all-ones B-frag (frees
// the VALU adds + epilogue shuffle). s_setprio(1) around MFMA clusters.
// ---------------------------------------------------------------------------
__device__ __forceinline__ void stage_kv(char* KbB, char* VtB,
    const bf16* __restrict__ Kp, const bf16* __restrict__ VpT,
    size_t headoff, size_t vbase, int kb, int w, int lane)
{
#pragma unroll
  for (int c = 0; c < 4; ++c) {
    const int rowK = c * 32 + w * 8 + (lane >> 3);
    const int segK = (lane & 7) ^ (rowK & 7);
    async_lds16(KbB + c * 4096 + w * 1024,
                Kp + headoff + (size_t)(kb + rowK) * Dd + segK * 8);
    const int rowV = c * 16 + w * 4 + (lane >> 4);
    const int segV = (lane & 15) ^ (rowV & 15);
    async_lds16(VtB + c * 4096 + w * 1024,
                VpT + vbase + (size_t)rowV * 2048 + kb + segV * 8);
  }
}

__global__ __launch_bounds__(256, 2)
void attn(const bf16* __restrict__ Qp, const bf16* __restrict__ Kp,
          const bf16* __restrict__ VpT, const uint32_t* __restrict__ mbits,
          bf16* __restrict__ Opart, float* __restrict__ Lpart)
{
  __shared__ char smem[65536];

  const int tile  = blockIdx.x;           // 512 = b*256 + h*16 + qt
  const int split = blockIdx.y;           // 2
  const int qt = tile & 15, h = (tile >> 4) & 15, b = tile >> 8;
  const int tid = threadIdx.x, w = tid >> 6, lane = tid & 63;
  const int quad = lane >> 4, l16 = lane & 15;
  const int qb = qt * 128;
  const size_t headoff = (size_t)b * (Ss * Dd) + h * DKk;
  const size_t vbase = (size_t)b * 2097152 + (size_t)h * 131072;

  const int kc0 = split * 8;
  const int kc1 = kc0 + 8;

  // Q B-frags, two sets of 16 q: lane holds Q[q][k = s2*32 + quad*8 + j]
  bf16x8 qf[2][2];
#pragma unroll
  for (int set = 0; set < 2; ++set)
#pragma unroll
    for (int s2 = 0; s2 < 2; ++s2) {
      const int row = qb + w * 32 + set * 16 + l16;
      qf[set][s2] = *(const bf16x8*)(Qp + headoff + (size_t)row * Dd + s2 * 32 + quad * 8);
    }

  // all-ones B-frag for the L-sum MFMA (bf16 1.0 = 0x3F80)
  bf16x8 onesv;
#pragma unroll
  for (int j = 0; j < 8; ++j) onesv[j] = (short)0x3F80;

  f32x4 o[2][4];
  f32x4 oL[2];
#pragma unroll
  for (int set = 0; set < 2; ++set) {
    oL[set] = f32x4{0.f, 0.f, 0.f, 0.f};
#pragma unroll
    for (int nbk = 0; nbk < 4; ++nbk) o[set][nbk] = f32x4{0.f, 0.f, 0.f, 0.f};
  }

  const uint32_t* mrow0 = mbits + (size_t)(b * Ss + qb + w * 32 + l16) * 64;
  const uint32_t* mrow1 = mrow0 + 16 * 64;

  // double-buffer pointers
  char* KbC = smem;
  char* VtC = smem + 16384;
  char* KbN = smem + 32768;
  char* VtN = smem + 49152;

  // prologue: mask words + K/V stage for first chunk
  uint4 mc0v = *(const uint4*)(mrow0 + kc0 * 4);
  uint4 mc1v = *(const uint4*)(mrow1 + kc0 * 4);
  stage_kv(KbC, VtC, Kp, VpT, headoff, vbase, kc0 * 128, w, lane);

  for (int kc = kc0; kc < kc1; ++kc) {
    uint4 mn0v = mc0v, mn1v = mc1v;
    if (kc + 1 < kc1) {
      mn0v = *(const uint4*)(mrow0 + (kc + 1) * 4);
      mn1v = *(const uint4*)(mrow1 + (kc + 1) * 4);
      stage_kv(KbN, VtN, Kp, VpT, headoff, vbase, (kc + 1) * 128, w, lane);
      // current buffer (8 oldest loads) + masks done; 8 prefetch stay in flight
      asm volatile("s_waitcnt vmcnt(8)" ::: "memory");
    } else {
      asm volatile("s_waitcnt vmcnt(0)" ::: "memory");
    }
    __builtin_amdgcn_s_barrier();
    __builtin_amdgcn_sched_barrier(0);

    const uint32_t mc0a[4] = {mc0v.x, mc0v.y, mc0v.z, mc0v.w};
    const uint32_t mc1a[4] = {mc1v.x, mc1v.y, mc1v.z, mc1v.w};

    // per 32-key slice: QK -> masked exp2 -> in-reg P frag -> PV (+L MFMA)
#pragma unroll
    for (int sl = 0; sl < 4; ++sl) {
      f32x4 sc[2][2];
#pragma unroll
      for (int set = 0; set < 2; ++set)
#pragma unroll
        for (int nbh = 0; nbh < 2; ++nbh) sc[set][nbh] = f32x4{0.f, 0.f, 0.f, 0.f};
      __builtin_amdgcn_s_setprio(1);
#pragma unroll
      for (int s2 = 0; s2 < 2; ++s2)
#pragma unroll
        for (int nbh = 0; nbh < 2; ++nbh) {
          const int row = (sl * 2 + nbh) * 16 + l16;
          bf16x8 kf = *(const bf16x8*)(KbC + row * 128 + (((s2 * 4 + quad) ^ (row & 7)) * 16));
          sc[0][nbh] = __builtin_amdgcn_mfma_f32_16x16x32_bf16(kf, qf[0][s2], sc[0][nbh], 0, 0, 0);
          sc[1][nbh] = __builtin_amdgcn_mfma_f32_16x16x32_bf16(kf, qf[1][s2], sc[1][nbh], 0, 0, 0);
        }
      __builtin_amdgcn_s_setprio(0);

      bf16x8 pf[2];
#pragma unroll
      for (int set = 0; set < 2; ++set) {
        const uint32_t mword = (set == 0) ? mc0a[sl] : mc1a[sl];
        uint32_t pk[2][2];   // [nbh][word]: quad q holds keys nb*16+q*4+{0..3}
#pragma unroll
        for (int nbh = 0; nbh < 2; ++nbh) {
          const uint32_t nib = (mword >> (nbh * 16 + quad * 4)) & 0xFu;
          const float e0 = __builtin_amdgcn_exp2f(sc[set][nbh][0]);
          const float e1 = __builtin_amdgcn_exp2f(sc[set][nbh][1]);
          const float e2 = __builtin_amdgcn_exp2f(sc[set][nbh][2]);
          const float e3 = __builtin_amdgcn_exp2f(sc[set][nbh][3]);
          const float p0 = (nib & 1u) ? e0 : 0.f;
          const float p1 = (nib & 2u) ? e1 : 0.f;
          const float p2 = (nib & 4u) ? e2 : 0.f;
          const float p3 = (nib & 8u) ? e3 : 0.f;
          pk[nbh][0] = cvtpk_bf16(p0, p1);
          pk[nbh][1] = cvtpk_bf16(p2, p3);
        }
        // quad redistribution: source quad q has keys q*4+{0..3} per nb;
        // target quad q needs keys q*8+{0..7} of the 32-key slice.
        const uint32x2 r0 = pl32swap(pk[0][0], pk[1][0]);
        const uint32x2 r1 = pl32swap(pk[0][1], pk[1][1]);
        const uint32x2 t0 = pl16swap(r0.x, r0.y);
        const uint32x2 t1 = pl16swap(r1.x, r1.y);
        union { uint32_t u[4]; bf16x8 v; } U;
        U.u[0] = t0.x; U.u[1] = t1.x; U.u[2] = t0.y; U.u[3] = t1.y;
        pf[set] = U.v;
      }

      // PV + L-sum for this slice; vf shared across both q-sets
      __builtin_amdgcn_s_setprio(1);
      oL[0] = __builtin_amdgcn_mfma_f32_16x16x32_bf16(pf[0], onesv, oL[0], 0, 0, 0);
      oL[1] = __builtin_amdgcn_mfma_f32_16x16x32_bf16(pf[1], onesv, oL[1], 0, 0, 0);
#pragma unroll
      for (int nbk = 0; nbk < 4; ++nbk) {
        const int row = nbk * 16 + l16;
        bf16x8 vf = *(const bf16x8*)(VtC + row * 256 + (((sl * 4 + quad) ^ (row & 15)) * 16));
        o[0][nbk] = __builtin_amdgcn_mfma_f32_16x16x32_bf16(pf[0], vf, o[0][nbk], 0, 0, 0);
        o[1][nbk] = __builtin_amdgcn_mfma_f32_16x16x32_bf16(pf[1], vf, o[1][nbk], 0, 0, 0);
      }
      __builtin_amdgcn_s_setprio(0);
    }

    asm volatile("" ::: "memory");
    __builtin_amdgcn_s_barrier();   // all reads of cur done before restage

    // rotate buffers + mask words
    char* tp;
    tp = KbC; KbC = KbN; KbN = tp;
    tp = VtC; VtC = VtN; VtN = tp;
    mc0v = mn0v; mc1v = mn1v;
  }

  // epilogue: write partials (rows = tile*128 + qlocal); L comes from oL
#pragma unroll
  for (int set = 0; set < 2; ++set) {
    const int rbase = tile * 128 + w * 32 + set * 16;
#pragma unroll
    for (int r = 0; r < 4; ++r) {
      const int rglob = rbase + quad * 4 + r;
#pragma unroll
      for (int nbk = 0; nbk < 4; ++nbk) {
        short s = f2bf_fast(o[set][nbk][r]);
        ((short*)Opart)[((size_t)split * 65536 + rglob) * 64 + nbk * 16 + l16] = s;
      }
    }
    if (l16 == 0) {
#pragma unroll
      for (int r = 0; r < 4; ++r)
        Lpart[(size_t)split * 65536 + rbase + quad * 4 + r] = oL[set][r];
    }
  }
}

// ---------------------------------------------------------------------------
// Combine 2 split partials (plain sums) -> Xa[b*S+q][h*64+dk] bf16.
// ---------------------------------------------------------------------------
__global__ __launch_bounds__(256)
void combine(const bf16* __restrict__ Opart, const float* __restrict__ Lpart,
             bf16* __restrict__ Xa)
{
  const int t = threadIdx.x;
  const int row = blockIdx.x * 32 + (t >> 3);     // 0..65535
  const int dkc = (t & 7) * 8;
  const float L = Lpart[row] + Lpart[65536 + row];
  const float inv = 1.0f / L;
  const bf16x8 O0 = *(const bf16x8*)(Opart + (size_t)row * 64 + dkc);
  const bf16x8 O1 = *(const bf16x8*)(Opart + ((size_t)65536 + row) * 64 + dkc);
  bf16x8 res;
#pragma unroll
  for (int j = 0; j < 8; ++j)
    res[j] = f2bf_fast((bfs2f(O0[j]) + bfs2f(O1[j])) * inv);
  const int tile = row >> 7, qlocal = row & 127;
  const int b = tile >> 8, h = (tile >> 4) & 15, q = (tile & 15) * 128 + qlocal;
  *(bf16x8*)(Xa + (size_t)(b * 2048 + q) * 1024 + h * 64 + dkc) = res;
}

// ---------------------------------------------------------------------------
extern "C" void kernel_launch(void* const* d_in, const int* in_sizes, int n_in,
                              void* d_out, int out_size, void* d_ws, size_t ws_size,
                              hipStream_t stream)
{
  const float* q  = (const float*)d_in[0];
  const float* k  = (const float*)d_in[1];
  const float* v  = (const float*)d_in[2];
  const int*   mk = (const int*)d_in[3];
  const float* wq = (const float*)d_in[4];
  const float* bq = (const float*)d_in[5];
  const float* wk = (const float*)d_in[6];
  const float* bk = (const float*)d_in[7];
  const float* wv = (const float*)d_in[8];
  const float* bv = (const float*)d_in[9];
  const float* wo = (const float*)d_in[10];
  const float* bo = (const float*)d_in[11];
  float* out = (float*)d_out;

  char* ws = (char*)d_ws;
  // phase-1 buffers
  bf16* qb_  = (bf16*)(ws + ((size_t)0  << 20));
  bf16* kb_  = (bf16*)(ws + ((size_t)8  << 20));
  bf16* vb_  = (bf16*)(ws + ((size_t)16 << 20));
  bf16* Qp   = (bf16*)(ws + ((size_t)24 << 20));
  bf16* Kp   = (bf16*)(ws + ((size_t)32 << 20));
  bf16* VpT  = (bf16*)(ws + ((size_t)40 << 20));
  bf16* wqb  = (bf16*)(ws + ((size_t)48 << 20));
  bf16* wkb  = (bf16*)(ws + ((size_t)50 << 20));
  bf16* wvb  = (bf16*)(ws + ((size_t)52 << 20));
  bf16* wob  = (bf16*)(ws + ((size_t)54 << 20));
  bf16* bqb  = (bf16*)(ws + ((size_t)56 << 20));
  bf16* bkb  = (bf16*)(ws + ((size_t)56 << 20) + 2048);
  bf16* bvb  = (bf16*)(ws + ((size_t)56 << 20) + 4096);
  bf16* bob  = (bf16*)(ws + ((size_t)56 << 20) + 6144);
  uint32_t* mbits = (uint32_t*)(ws + ((size_t)56 << 20) + 65536);  // 1 MB
  // phase-2 overlays: Opart 16MB over qb_/kb_ (dead after QKV GEMM);
  // Lpart 0.5MB over wqb (dead); Xa 8MB over Qp (dead after attn)
  bf16*  Opart = (bf16*)(ws + ((size_t)0 << 20));
  float* Lpart = (float*)(ws + ((size_t)48 << 20));
  bf16*  Xa    = (bf16*)(ws + ((size_t)24 << 20));

  const int NA = Bb * Ss * Dd;  // 4194304
  const int NW = Dd * Dd;       // 1048576

  CvtArgs ca;
  ca.src[0] = q;  ca.dst[0] = (short*)qb_; ca.n[0] = NA;
  ca.src[1] = k;  ca.dst[1] = (short*)kb_; ca.n[1] = NA;
  ca.src[2] = v;  ca.dst[2] = (short*)vb_; ca.n[2] = NA;
  ca.src[3] = wq; ca.dst[3] = (short*)wqb; ca.n[3] = NW;
  ca.src[4] = wk; ca.dst[4] = (short*)wkb; ca.n[4] = NW;
  ca.src[5] = wv; ca.dst[5] = (short*)wvb; ca.n[5] = NW;
  ca.src[6] = wo; ca.dst[6] = (short*)wob; ca.n[6] = NW;
  ca.src[7] = bq; ca.dst[7] = (short*)bqb; ca.n[7] = Dd;
  ca.src[8] = bk; ca.dst[8] = (short*)bkb; ca.n[8] = Dd;
  ca.src[9] = bv; ca.dst[9] = (short*)bvb; ca.n[9] = Dd;
  ca.src[10] = bo; ca.dst[10] = (short*)bob; ca.n[10] = Dd;
  ca.src[11] = bo; ca.dst[11] = (short*)bob; ca.n[11] = 0;
  ca.count = 11;

  dim3 blk(256);
  // conversions + mask pack (job 11) in one launch
  cvt_all<<<dim3(1024, 12), blk, 0, stream>>>(ca, mk, mbits);

  // fused QKV projections; Q scaled by log2e/8 (softmax runs in base 2),
  // V written transposed via LDS
  gemm_bt<<<dim3(32, 24), blk, 32768, stream>>>(qb_, kb_, vb_, wqb, wkb, wvb,
                                                bqb, bkb, bvb,
                                                (void*)Qp, (void*)Kp, (void*)VpT,
                                                0.125f * 1.44269504088896340736f, 1);
  // split-K flash attention (2 splits x 8 chunks), double-buffered K/V,
  // counted vmcnt pipeline, P in registers, L via ones-MFMA
  attn<<<dim3(512, 2), blk, 0, stream>>>(Qp, Kp, VpT, mbits, Opart, Lpart);
  // merge split partials
  combine<<<dim3(2048), blk, 0, stream>>>(Opart, Lpart, Xa);
  // output projection -> f32 d_out (64x64 tiles, 1024 blocks = 4/CU)
  gemm_out<<<dim3(64, 16), blk, 0, stream>>>(Xa, wob, bob, out);
}